// Round 1
// baseline (83629.321 us; speedup 1.0000x reference)
//
#include <hip/hip_runtime.h>
#include <stdint.h>

#define NBLK 256
#define NTHR 512          // 8 waves: K-split within block
#define BATCH 64
#define HD 1024
#define SEQ 512

typedef unsigned short u16;
typedef __attribute__((ext_vector_type(8))) short v8s;   // 8 bf16 = 4 VGPRs (MFMA A/B frag)
typedef __attribute__((ext_vector_type(4))) float v4f;   // MFMA C/D frag

__device__ __forceinline__ float bf2f(u16 u){
  union { float f; uint32_t i; } c; c.i = ((uint32_t)u) << 16; return c.f;
}
__device__ __forceinline__ u16 f2bf(float f){  // round-to-nearest-even
  union { float f; uint32_t i; } c; c.f = f;
  uint32_t i = c.i;
  return (u16)((i + 0x7fffu + ((i >> 16) & 1u)) >> 16);
}
__device__ __forceinline__ float sigm(float v){ return 1.f / (1.f + __expf(-v)); }

// ---- grid barrier: per-block flag slots, monotonic target, agent scope ----
__device__ __forceinline__ void gbar(int* flags, int target, int bid, int tid){
  __syncthreads();                       // all waves' stores drained (vmcnt) & block done
  if (tid == 0){
    __threadfence();                     // flush this XCD's dirty L2 lines to coherent point
    __hip_atomic_store(&flags[bid], target, __ATOMIC_RELEASE, __HIP_MEMORY_SCOPE_AGENT);
  }
  if (tid < 64){                         // wave 0 polls all 256 flags (4 per lane)
    int* p = flags + tid * 4;
    for (;;){
      int a = __hip_atomic_load(p + 0, __ATOMIC_RELAXED, __HIP_MEMORY_SCOPE_AGENT);
      int b = __hip_atomic_load(p + 1, __ATOMIC_RELAXED, __HIP_MEMORY_SCOPE_AGENT);
      int c = __hip_atomic_load(p + 2, __ATOMIC_RELAXED, __HIP_MEMORY_SCOPE_AGENT);
      int d = __hip_atomic_load(p + 3, __ATOMIC_RELAXED, __HIP_MEMORY_SCOPE_AGENT);
      if (a >= target && b >= target && c >= target && d >= target) break;
      __builtin_amdgcn_s_sleep(1);
    }
    __threadfence();                     // acquire: invalidate stale L1/L2 before reading peers' data
  }
  __syncthreads();
}

// ---- one mogrify matmul phase: O = 2*sigmoid(A @ W) * mult, all [64][1024] ----
// A as hi/lo bf16 pair; W as pre-transposed hi/lo WT[n][k]; mult either fp32 (x slice) or hi/lo pair.
__device__ __forceinline__ void mog_phase(
    const u16* Ahi, const u16* Alo,
    const u16* WThi, const u16* WTlo,
    const float* multf32,                // if non-null: x + t*HD, row stride SEQ*HD
    const u16* Mhi, const u16* Mlo,
    u16* Ohi, u16* Olo,
    int rm, int cn, int tid, float* cb)
{
  const int w = tid >> 6, lane = tid & 63;
  const int mi = lane & 15, q = lane >> 4;
  const int kb = w * 128 + q * 8;        // wave w owns K slice [w*128, w*128+128)
  const u16* ah_p = Ahi + (size_t)(rm + mi) * HD + kb;
  const u16* al_p = Alo + (size_t)(rm + mi) * HD + kb;
  const u16* bh_p = WThi + (size_t)(cn + mi) * HD + kb;
  const u16* bl_p = WTlo + (size_t)(cn + mi) * HD + kb;
  v4f acc = {0.f, 0.f, 0.f, 0.f};
#pragma unroll
  for (int ks = 0; ks < 4; ks++){
    const int k = ks * 32;
    v8s ah = *(const v8s*)(ah_p + k);
    v8s al = *(const v8s*)(al_p + k);
    v8s bh = *(const v8s*)(bh_p + k);
    v8s bl = *(const v8s*)(bl_p + k);
    acc = __builtin_amdgcn_mfma_f32_16x16x32_bf16(ah, bh, acc, 0, 0, 0);
    acc = __builtin_amdgcn_mfma_f32_16x16x32_bf16(ah, bl, acc, 0, 0, 0);
    acc = __builtin_amdgcn_mfma_f32_16x16x32_bf16(al, bh, acc, 0, 0, 0);
  }
  // partial C frag -> LDS  (C/D layout: col = lane&15, row = (lane>>4)*4 + reg)
  float* dst = cb + w * 1088;            // [w][16][17]
#pragma unroll
  for (int r = 0; r < 4; r++) dst[(q * 4 + r) * 17 + mi] = acc[r];
  __syncthreads();
  if (tid < 256){
    const int r = tid >> 4, c = tid & 15;
    float v = 0.f;
#pragma unroll
    for (int w2 = 0; w2 < 8; w2++) v += cb[w2 * 1088 + r * 17 + c];
    const float s = 2.f * sigm(v);
    const int gi = (rm + r) * HD + (cn + c);
    const float mult = multf32 ? multf32[(size_t)(rm + r) * (SEQ * HD) + (cn + c)]
                               : (bf2f(Mhi[gi]) + bf2f(Mlo[gi]));
    const float o = s * mult;
    const u16 hi = f2bf(o);
    Ohi[gi] = hi;
    Olo[gi] = f2bf(o - bf2f(hi));
  }
}

// ---- gates + fused LSTM cell.  Block owns rows rm..rm+15, cols cn..cn+15 of h/C,
//      i.e. gate cols {q*1024 + cn .. +15} for q=0..3.  8 waves: 4 on x@Wih, 4 on h@Whh, K-split 256.
__device__ __forceinline__ void gates_phase(
    const u16* Xhi, const u16* Xlo,      // xt3
    const u16* Hhi, const u16* Hlo,      // ht2
    const u16* WihThi, const u16* WihTlo,
    const u16* WhhThi, const u16* WhhTlo,
    const float* bih, const float* bhh,
    float* C, u16* Ohi, u16* Olo,
    int rm, int cn, int tid, float* cb, float* red)
{
  const int w = tid >> 6, lane = tid & 63;
  const int mi = lane & 15, q = lane >> 4;
  const int src = w >> 2;
  const u16* Ah = src ? Hhi : Xhi;
  const u16* Al = src ? Hlo : Xlo;
  const u16* Bh = src ? WhhThi : WihThi;
  const u16* Bl = src ? WhhTlo : WihTlo;
  const int kb = (w & 3) * 256 + q * 8;
  const u16* ah_p = Ah + (size_t)(rm + mi) * HD + kb;
  const u16* al_p = Al + (size_t)(rm + mi) * HD + kb;
  const u16* bh_p[4]; const u16* bl_p[4];
#pragma unroll
  for (int nt = 0; nt < 4; nt++){
    const size_t brow = (size_t)(nt * HD + cn + mi) * HD + kb;
    bh_p[nt] = Bh + brow; bl_p[nt] = Bl + brow;
  }
  v4f acc[4];
#pragma unroll
  for (int nt = 0; nt < 4; nt++) acc[nt] = (v4f){0.f, 0.f, 0.f, 0.f};
#pragma unroll
  for (int ks = 0; ks < 8; ks++){
    const int k = ks * 32;
    v8s ah = *(const v8s*)(ah_p + k);
    v8s al = *(const v8s*)(al_p + k);
#pragma unroll
    for (int nt = 0; nt < 4; nt++){
      v8s bh = *(const v8s*)(bh_p[nt] + k);
      v8s bl = *(const v8s*)(bl_p[nt] + k);
      acc[nt] = __builtin_amdgcn_mfma_f32_16x16x32_bf16(ah, bh, acc[nt], 0, 0, 0);
      acc[nt] = __builtin_amdgcn_mfma_f32_16x16x32_bf16(ah, bl, acc[nt], 0, 0, 0);
      acc[nt] = __builtin_amdgcn_mfma_f32_16x16x32_bf16(al, bh, acc[nt], 0, 0, 0);
    }
  }
#pragma unroll
  for (int nt = 0; nt < 4; nt++)
#pragma unroll
    for (int r = 0; r < 4; r++)
      cb[(w * 4 + nt) * 272 + (q * 4 + r) * 17 + mi] = acc[nt][r];
  __syncthreads();
  for (int e = tid; e < 1024; e += NTHR){
    const int qq = e >> 8, rc = e & 255, r = rc >> 4, c = rc & 15;
    float v = 0.f;
#pragma unroll
    for (int w2 = 0; w2 < 8; w2++) v += cb[(w2 * 4 + qq) * 272 + r * 17 + c];
    red[qq * 272 + r * 17 + c] = v;
  }
  __syncthreads();
  if (tid < 256){
    const int r = tid >> 4, c = tid & 15;
    const int col = cn + c;
    const float g0 = red[0 * 272 + r * 17 + c] + bih[col]          + bhh[col];
    const float g1 = red[1 * 272 + r * 17 + c] + bih[HD + col]     + bhh[HD + col];
    const float g2 = red[2 * 272 + r * 17 + c] + bih[2 * HD + col] + bhh[2 * HD + col];
    const float g3 = red[3 * 272 + r * 17 + c] + bih[3 * HD + col] + bhh[3 * HD + col];
    const float ig = sigm(g0), fg = sigm(g1), cg = tanhf(g2), og = sigm(g3);
    const int gi = (rm + r) * HD + col;
    const float cnew = fg * C[gi] + ig * cg;
    C[gi] = cnew;
    const float h = og * tanhf(cnew);
    const u16 hi = f2bf(h);
    Ohi[gi] = hi;
    Olo[gi] = f2bf(h - bf2f(hi));
  }
}

extern "C" __global__ void __launch_bounds__(NTHR, 2)
moglstm_kernel(const float* __restrict__ x, const float* __restrict__ Wih,
               const float* __restrict__ Whh, const float* __restrict__ bih,
               const float* __restrict__ bhh, const float* __restrict__ Q,
               const float* __restrict__ Rw, const float* __restrict__ h0,
               const float* __restrict__ c0, float* __restrict__ out,
               uint8_t* __restrict__ ws)
{
  __shared__ float cb[32 * 272];         // 8 waves x 4 tiles x [16][17] partials
  __shared__ float red[4 * 272];
  __shared__ u16 shh[32 * 33], shl[32 * 33];

  // ---- carve workspace ----
  uint8_t* p = ws;
  float* C   = (float*)p;  p += (size_t)BATCH * HD * 4;
  u16* xAhi  = (u16*)p;    p += (size_t)BATCH * HD * 2;
  u16* xAlo  = (u16*)p;    p += (size_t)BATCH * HD * 2;
  u16* xBhi  = (u16*)p;    p += (size_t)BATCH * HD * 2;
  u16* xBlo  = (u16*)p;    p += (size_t)BATCH * HD * 2;
  u16* hAhi  = (u16*)p;    p += (size_t)BATCH * HD * 2;
  u16* hAlo  = (u16*)p;    p += (size_t)BATCH * HD * 2;
  u16* hBhi  = (u16*)p;    p += (size_t)BATCH * HD * 2;
  u16* hBlo  = (u16*)p;    p += (size_t)BATCH * HD * 2;
  u16* QThi  = (u16*)p;    p += (size_t)HD * HD * 2;
  u16* QTlo  = (u16*)p;    p += (size_t)HD * HD * 2;
  u16* RThi  = (u16*)p;    p += (size_t)HD * HD * 2;
  u16* RTlo  = (u16*)p;    p += (size_t)HD * HD * 2;
  u16* WihThi = (u16*)p;   p += (size_t)4 * HD * HD * 2;
  u16* WihTlo = (u16*)p;   p += (size_t)4 * HD * HD * 2;
  u16* WhhThi = (u16*)p;   p += (size_t)4 * HD * HD * 2;
  u16* WhhTlo = (u16*)p;   p += (size_t)4 * HD * HD * 2;
  int* flags = (int*)p;

  const int bid = blockIdx.x, tid = threadIdx.x;
  const int rm = (bid >> 6) * 16, cn = (bid & 63) * 16;

  // ---- prep: split weights into hi/lo bf16 + transpose to WT[n][k]; init h/C ----
  // 10240 tiles of 32x32: [0,1024) Q, [1024,2048) R, [2048,6144) Wih, [6144,10240) Whh
  for (int tile = bid; tile < 10240; tile += NBLK){
    const float* W; u16 *Th, *Tl; int N, kt, nt;
    if (tile < 1024)      { W = Q;   Th = QThi;   Tl = QTlo;   N = HD;     int tl = tile;        kt = tl >> 5; nt = tl & 31; }
    else if (tile < 2048) { W = Rw;  Th = RThi;   Tl = RTlo;   N = HD;     int tl = tile - 1024; kt = tl >> 5; nt = tl & 31; }
    else if (tile < 6144) { W = Wih; Th = WihThi; Tl = WihTlo; N = 4 * HD; int tl = tile - 2048; kt = tl >> 7; nt = tl & 127; }
    else                  { W = Whh; Th = WhhThi; Tl = WhhTlo; N = 4 * HD; int tl = tile - 6144; kt = tl >> 7; nt = tl & 127; }
    for (int e = tid; e < 1024; e += NTHR){
      const int ki = e >> 5, nj = e & 31;
      const float v = W[(size_t)(kt * 32 + ki) * N + nt * 32 + nj];
      const u16 hi = f2bf(v);
      shh[ki * 33 + nj] = hi;
      shl[ki * 33 + nj] = f2bf(v - bf2f(hi));
    }
    __syncthreads();
    for (int e = tid; e < 1024; e += NTHR){
      const int ni = e >> 5, kj = e & 31;
      Th[(size_t)(nt * 32 + ni) * HD + kt * 32 + kj] = shh[kj * 33 + ni];
      Tl[(size_t)(nt * 32 + ni) * HD + kt * 32 + kj] = shl[kj * 33 + ni];
    }
    __syncthreads();
  }
  for (int i = bid * NTHR + tid; i < BATCH * HD; i += NBLK * NTHR){
    C[i] = c0[i];
    const float h = h0[i];
    const u16 hi = f2bf(h);
    hAhi[i] = hi;
    hAlo[i] = f2bf(h - bf2f(hi));
  }
  int bar = 1;
  gbar(flags, bar, bid, tid);

  // ---- recurrence ----
  u16 *hch = hAhi, *hcl = hAlo, *hoh = hBhi, *hol = hBlo;
  for (int t = 0; t < SEQ; t++){
    // i=1: xt1 = 2s(ht0@Q)*x[:,t,:]
    mog_phase(hch, hcl, QThi, QTlo, x + (size_t)t * HD, nullptr, nullptr, xAhi, xAlo, rm, cn, tid, cb);
    bar++; gbar(flags, bar, bid, tid);
    // i=2: ht1 = 2s(xt1@R)*ht0
    mog_phase(xAhi, xAlo, RThi, RTlo, nullptr, hch, hcl, hoh, hol, rm, cn, tid, cb);
    bar++; gbar(flags, bar, bid, tid);
    // i=3: xt2 = 2s(ht1@Q)*xt1
    mog_phase(hoh, hol, QThi, QTlo, nullptr, xAhi, xAlo, xBhi, xBlo, rm, cn, tid, cb);
    bar++; gbar(flags, bar, bid, tid);
    // i=4: ht2 = 2s(xt2@R)*ht1   (overwrites ht0, dead)
    mog_phase(xBhi, xBlo, RThi, RTlo, nullptr, hoh, hol, hch, hcl, rm, cn, tid, cb);
    bar++; gbar(flags, bar, bid, tid);
    // i=5: xt3 = 2s(ht2@Q)*xt2   (overwrites xt1, dead)
    mog_phase(hch, hcl, QThi, QTlo, nullptr, xBhi, xBlo, xAhi, xAlo, rm, cn, tid, cb);
    bar++; gbar(flags, bar, bid, tid);
    // gates + cell: h_new -> other h buffer
    gates_phase(xAhi, xAlo, hch, hcl, WihThi, WihTlo, WhhThi, WhhTlo, bih, bhh,
                C, hoh, hol, rm, cn, tid, cb, red);
    bar++; gbar(flags, bar, bid, tid);
    u16* t1 = hch; hch = hoh; hoh = t1;
    u16* t2 = hcl; hcl = hol; hol = t2;
  }

  // ---- output: h_final (fp32 = hi + lo) ----
  for (int i = bid * NTHR + tid; i < BATCH * HD; i += NBLK * NTHR)
    out[i] = bf2f(hch[i]) + bf2f(hcl[i]);
}

extern "C" void kernel_launch(void* const* d_in, const int* in_sizes, int n_in,
                              void* d_out, int out_size, void* d_ws, size_t ws_size,
                              hipStream_t stream)
{
  const float* x   = (const float*)d_in[0];
  const float* Wih = (const float*)d_in[1];
  const float* Whh = (const float*)d_in[2];
  const float* bih = (const float*)d_in[3];
  const float* bhh = (const float*)d_in[4];
  const float* Q   = (const float*)d_in[5];
  const float* Rw  = (const float*)d_in[6];
  const float* h0  = (const float*)d_in[7];
  const float* c0  = (const float*)d_in[8];
  // d_in[9] = mog_iterations (always 5, hardcoded)
  float* out = (float*)d_out;
  uint8_t* ws = (uint8_t*)d_ws;
  void* args[] = { &x, &Wih, &Whh, &bih, &bhh, &Q, &Rw, &h0, &c0, &out, &ws };
  hipLaunchCooperativeKernel((void*)moglstm_kernel, dim3(NBLK), dim3(NTHR),
                             args, 0, stream);
}

// Round 2
// 53319.458 us; speedup vs baseline: 1.5685x; 1.5685x over previous
//
#include <hip/hip_runtime.h>
#include <stdint.h>

#define NBLK 256
#define NTHR 512          // 8 waves: K-split within block
#define BATCH 64
#define HD 1024
#define SEQ 512

typedef unsigned short u16;
typedef uint32_t u32;
typedef __attribute__((ext_vector_type(8))) short v8s;   // 8 bf16 = 4 VGPRs (MFMA A/B frag)
typedef __attribute__((ext_vector_type(4))) float v4f;   // MFMA C/D frag

__device__ __forceinline__ float bf2f(u16 u){
  union { float f; u32 i; } c; c.i = ((u32)u) << 16; return c.f;
}
__device__ __forceinline__ u16 f2bf(float f){  // round-to-nearest-even
  union { float f; u32 i; } c; c.f = f;
  u32 i = c.i;
  return (u16)((i + 0x7fffu + ((i >> 16) & 1u)) >> 16);
}
__device__ __forceinline__ float sigm(float v){ return 1.f / (1.f + __expf(-v)); }

// packed activation element: low16 = hi bf16, high16 = lo bf16; value = hi + lo
__device__ __forceinline__ u32 packf(float v){
  const u16 hi = f2bf(v);
  const u16 lo = f2bf(v - bf2f(hi));
  return (u32)hi | ((u32)lo << 16);
}
__device__ __forceinline__ float unpackf(u32 w){
  return bf2f((u16)(w & 0xffffu)) + bf2f((u16)(w >> 16));
}

// coherent (agent-scope, cache-bypassing) access — no fences required
__device__ __forceinline__ u32 ald(const u32* p){
  return __hip_atomic_load(p, __ATOMIC_RELAXED, __HIP_MEMORY_SCOPE_AGENT);
}
__device__ __forceinline__ void ast(u32* p, u32 v){
  __hip_atomic_store(p, v, __ATOMIC_RELAXED, __HIP_MEMORY_SCOPE_AGENT);
}
__device__ __forceinline__ int aldi(const int* p){
  return __hip_atomic_load(p, __ATOMIC_RELAXED, __HIP_MEMORY_SCOPE_AGENT);
}

struct FragPair { v8s hi; v8s lo; };
// load 8 packed u32 -> (8 hi bf16, 8 lo bf16) MFMA frags
__device__ __forceinline__ FragPair load_packed8(const u32* p){
  u32 w[8];
#pragma unroll
  for (int i = 0; i < 8; i++) w[i] = ald(p + i);
  union { v8s v; u32 u[4]; } H, L;
#pragma unroll
  for (int i = 0; i < 4; i++){
    H.u[i] = (w[2*i] & 0xffffu) | (w[2*i+1] << 16);
    L.u[i] = (w[2*i] >> 16)     | (w[2*i+1] & 0xffff0000u);
  }
  FragPair f; f.hi = H.v; f.lo = L.v; return f;
}

// ---- fence-free grid barrier: per-block flag, monotonic target ----
// All loop-carried cross-block data moves via sc1 atomics, so __syncthreads()'s
// vmcnt(0) drain is the only ordering needed before the arrival store.
__device__ __forceinline__ void gbar(int* flags, int target, int bid, int tid){
  __syncthreads();
  if (tid == 0)
    __hip_atomic_store(&flags[bid], target, __ATOMIC_RELAXED, __HIP_MEMORY_SCOPE_AGENT);
  if (tid < 64){
    const int* p = flags + tid * 4;
    for (;;){
      int a = aldi(p + 0), b = aldi(p + 1), c = aldi(p + 2), d = aldi(p + 3);
      if (a >= target && b >= target && c >= target && d >= target) break;
      __builtin_amdgcn_s_sleep(1);
    }
  }
  __syncthreads();
}

// ---- one mogrify matmul phase: O = 2*sigmoid(A @ W) * mult, all [64][1024] ----
__device__ __forceinline__ void mog_phase(
    const u32* A,                        // packed activations
    const u16* WThi, const u16* WTlo,    // weights, plain cached loads (L2-resident)
    const float* multx,                  // if non-null: x + t*HD (row stride SEQ*HD)
    const u32* M,                        // else packed multiplier
    u32* O,
    int rm, int cn, int tid, float* cb)
{
  const int w = tid >> 6, lane = tid & 63;
  const int mi = lane & 15, q = lane >> 4;
  const int kb = w * 128 + q * 8;        // wave w owns K slice [w*128, w*128+128)
  const u32* a_p  = A    + (size_t)(rm + mi) * HD + kb;
  const u16* bh_p = WThi + (size_t)(cn + mi) * HD + kb;
  const u16* bl_p = WTlo + (size_t)(cn + mi) * HD + kb;
  v4f acc = {0.f, 0.f, 0.f, 0.f};
#pragma unroll
  for (int ks = 0; ks < 4; ks++){
    const int k = ks * 32;
    FragPair a = load_packed8(a_p + k);
    v8s bh = *(const v8s*)(bh_p + k);
    v8s bl = *(const v8s*)(bl_p + k);
    acc = __builtin_amdgcn_mfma_f32_16x16x32_bf16(a.hi, bh, acc, 0, 0, 0);
    acc = __builtin_amdgcn_mfma_f32_16x16x32_bf16(a.hi, bl, acc, 0, 0, 0);
    acc = __builtin_amdgcn_mfma_f32_16x16x32_bf16(a.lo, bh, acc, 0, 0, 0);
  }
  float* dst = cb + w * 1088;            // [w][16][17] partials
#pragma unroll
  for (int r = 0; r < 4; r++) dst[(q * 4 + r) * 17 + mi] = acc[r];
  __syncthreads();
  if (tid < 256){
    const int r = tid >> 4, c = tid & 15;
    float v = 0.f;
#pragma unroll
    for (int w2 = 0; w2 < 8; w2++) v += cb[w2 * 1088 + r * 17 + c];
    const float s = 2.f * sigm(v);
    const int gi = (rm + r) * HD + (cn + c);
    float mult;
    if (multx) mult = __builtin_nontemporal_load(multx + (size_t)(rm + r) * (SEQ * HD) + (cn + c));
    else       mult = unpackf(ald(M + gi));
    ast(O + gi, packf(s * mult));
  }
}

// ---- gates + fused LSTM cell.  Block owns rows rm..+15, cols cn..+15 of h/C. ----
__device__ __forceinline__ void gates_phase(
    const u32* X, const u32* H,          // xt3, ht2 packed
    const u16* WihThi, const u16* WihTlo,
    const u16* WhhThi, const u16* WhhTlo,
    const float* bsum,                   // per-thread hoisted bih+bhh (4 gates), tid<256
    float& creg, u32* O,
    int rm, int cn, int tid, float* cb, float* red)
{
  const int w = tid >> 6, lane = tid & 63;
  const int mi = lane & 15, q = lane >> 4;
  const int src = w >> 2;
  const u32* Ap = src ? H : X;
  const u16* Bh = src ? WhhThi : WihThi;
  const u16* Bl = src ? WhhTlo : WihTlo;
  const int kb = (w & 3) * 256 + q * 8;
  const u32* a_p = Ap + (size_t)(rm + mi) * HD + kb;
  const u16* bh_p[4]; const u16* bl_p[4];
#pragma unroll
  for (int nt = 0; nt < 4; nt++){
    const size_t brow = (size_t)(nt * HD + cn + mi) * HD + kb;
    bh_p[nt] = Bh + brow; bl_p[nt] = Bl + brow;
  }
  v4f acc[4];
#pragma unroll
  for (int nt = 0; nt < 4; nt++) acc[nt] = (v4f){0.f, 0.f, 0.f, 0.f};
#pragma unroll
  for (int ks = 0; ks < 8; ks++){
    const int k = ks * 32;
    FragPair a = load_packed8(a_p + k);
#pragma unroll
    for (int nt = 0; nt < 4; nt++){
      v8s bh = *(const v8s*)(bh_p[nt] + k);
      v8s bl = *(const v8s*)(bl_p[nt] + k);
      acc[nt] = __builtin_amdgcn_mfma_f32_16x16x32_bf16(a.hi, bh, acc[nt], 0, 0, 0);
      acc[nt] = __builtin_amdgcn_mfma_f32_16x16x32_bf16(a.hi, bl, acc[nt], 0, 0, 0);
      acc[nt] = __builtin_amdgcn_mfma_f32_16x16x32_bf16(a.lo, bh, acc[nt], 0, 0, 0);
    }
  }
#pragma unroll
  for (int nt = 0; nt < 4; nt++)
#pragma unroll
    for (int r = 0; r < 4; r++)
      cb[(w * 4 + nt) * 272 + (q * 4 + r) * 17 + mi] = acc[nt][r];
  __syncthreads();
  for (int e = tid; e < 1024; e += NTHR){
    const int qq = e >> 8, rc = e & 255, r = rc >> 4, c = rc & 15;
    float v = 0.f;
#pragma unroll
    for (int w2 = 0; w2 < 8; w2++) v += cb[(w2 * 4 + qq) * 272 + r * 17 + c];
    red[qq * 272 + r * 17 + c] = v;
  }
  __syncthreads();
  if (tid < 256){
    const int r = tid >> 4, c = tid & 15;
    const float g0 = red[0 * 272 + r * 17 + c] + bsum[0];
    const float g1 = red[1 * 272 + r * 17 + c] + bsum[1];
    const float g2 = red[2 * 272 + r * 17 + c] + bsum[2];
    const float g3 = red[3 * 272 + r * 17 + c] + bsum[3];
    const float ig = sigm(g0), fg = sigm(g1), cg = tanhf(g2), og = sigm(g3);
    const float cnew = fg * creg + ig * cg;
    creg = cnew;
    const float h = og * tanhf(cnew);
    ast(O + (rm + r) * HD + (cn + c), packf(h));
  }
}

extern "C" __global__ void __launch_bounds__(NTHR, 2)
moglstm_kernel(const float* __restrict__ x, const float* __restrict__ Wih,
               const float* __restrict__ Whh, const float* __restrict__ bih,
               const float* __restrict__ bhh, const float* __restrict__ Q,
               const float* __restrict__ Rw, const float* __restrict__ h0,
               const float* __restrict__ c0, float* __restrict__ out,
               uint8_t* __restrict__ ws)
{
  __shared__ float cb[32 * 272];         // 8 waves x 4 tiles x [16][17] partials
  __shared__ float red[4 * 272];
  __shared__ u16 shh[32 * 33], shl[32 * 33];

  // ---- carve workspace ----
  uint8_t* p = ws;
  u32* xA   = (u32*)p;     p += (size_t)BATCH * HD * 4;
  u32* xB   = (u32*)p;     p += (size_t)BATCH * HD * 4;
  u32* hA   = (u32*)p;     p += (size_t)BATCH * HD * 4;
  u32* hB   = (u32*)p;     p += (size_t)BATCH * HD * 4;
  u16* QThi  = (u16*)p;    p += (size_t)HD * HD * 2;
  u16* QTlo  = (u16*)p;    p += (size_t)HD * HD * 2;
  u16* RThi  = (u16*)p;    p += (size_t)HD * HD * 2;
  u16* RTlo  = (u16*)p;    p += (size_t)HD * HD * 2;
  u16* WihThi = (u16*)p;   p += (size_t)4 * HD * HD * 2;
  u16* WihTlo = (u16*)p;   p += (size_t)4 * HD * HD * 2;
  u16* WhhThi = (u16*)p;   p += (size_t)4 * HD * HD * 2;
  u16* WhhTlo = (u16*)p;   p += (size_t)4 * HD * HD * 2;
  int* flags = (int*)p;

  const int bid = blockIdx.x, tid = threadIdx.x;
  const int rm = (bid >> 6) * 16, cn = (bid & 63) * 16;

  // ---- prep: split weights into hi/lo bf16 + transpose to WT[n][k]; init h ----
  for (int tile = bid; tile < 10240; tile += NBLK){
    const float* W; u16 *Th, *Tl; int N, kt, nt;
    if (tile < 1024)      { W = Q;   Th = QThi;   Tl = QTlo;   N = HD;     int tl = tile;        kt = tl >> 5; nt = tl & 31; }
    else if (tile < 2048) { W = Rw;  Th = RThi;   Tl = RTlo;   N = HD;     int tl = tile - 1024; kt = tl >> 5; nt = tl & 31; }
    else if (tile < 6144) { W = Wih; Th = WihThi; Tl = WihTlo; N = 4 * HD; int tl = tile - 2048; kt = tl >> 7; nt = tl & 127; }
    else                  { W = Whh; Th = WhhThi; Tl = WhhTlo; N = 4 * HD; int tl = tile - 6144; kt = tl >> 7; nt = tl & 127; }
    for (int e = tid; e < 1024; e += NTHR){
      const int ki = e >> 5, nj = e & 31;
      const float v = W[(size_t)(kt * 32 + ki) * N + nt * 32 + nj];
      const u16 hi = f2bf(v);
      shh[ki * 33 + nj] = hi;
      shl[ki * 33 + nj] = f2bf(v - bf2f(hi));
    }
    __syncthreads();
    for (int e = tid; e < 1024; e += NTHR){
      const int ni = e >> 5, kj = e & 31;
      Th[(size_t)(nt * 32 + ni) * HD + kt * 32 + kj] = shh[kj * 33 + ni];
      Tl[(size_t)(nt * 32 + ni) * HD + kt * 32 + kj] = shl[kj * 33 + ni];
    }
    __syncthreads();
  }
  for (int i = bid * NTHR + tid; i < BATCH * HD; i += NBLK * NTHR)
    hA[i] = packf(h0[i]);

  // hoist cell state + bias sums into registers (block<->tile mapping is fixed)
  float creg = 0.f;
  float bsum[4] = {0.f, 0.f, 0.f, 0.f};
  if (tid < 256){
    const int r = tid >> 4, c = tid & 15, col = cn + c;
    creg = c0[(rm + r) * HD + col];
#pragma unroll
    for (int qq = 0; qq < 4; qq++) bsum[qq] = bih[qq * HD + col] + bhh[qq * HD + col];
  }

  // one-time heavyweight release: flush prep's normal stores (weights, hA) to
  // the coherent point so other XCDs' plain/sc1 loads see them.
  __threadfence();
  int bar = 1;
  gbar(flags, bar, bid, tid);

  // ---- recurrence (all cross-block data via sc1 atomics; no fences) ----
  u32 *hc = hA, *ho = hB;
  for (int t = 0; t < SEQ; t++){
    // i=1: xt1 = 2s(ht0@Q)*x[:,t,:]
    mog_phase(hc, QThi, QTlo, x + (size_t)t * HD, nullptr, xA, rm, cn, tid, cb);
    bar++; gbar(flags, bar, bid, tid);
    // i=2: ht1 = 2s(xt1@R)*ht0
    mog_phase(xA, RThi, RTlo, nullptr, hc, ho, rm, cn, tid, cb);
    bar++; gbar(flags, bar, bid, tid);
    // i=3: xt2 = 2s(ht1@Q)*xt1
    mog_phase(ho, QThi, QTlo, nullptr, xA, xB, rm, cn, tid, cb);
    bar++; gbar(flags, bar, bid, tid);
    // i=4: ht2 = 2s(xt2@R)*ht1   (overwrites ht0, dead)
    mog_phase(xB, RThi, RTlo, nullptr, ho, hc, rm, cn, tid, cb);
    bar++; gbar(flags, bar, bid, tid);
    // i=5: xt3 = 2s(ht2@Q)*xt2   (overwrites xt1, dead)
    mog_phase(hc, QThi, QTlo, nullptr, xB, xA, rm, cn, tid, cb);
    bar++; gbar(flags, bar, bid, tid);
    // gates + cell: h_new -> other h buffer
    gates_phase(xA, hc, WihThi, WihTlo, WhhThi, WhhTlo, bsum, creg, ho,
                rm, cn, tid, cb, red);
    bar++; gbar(flags, bar, bid, tid);
    u32* tswp = hc; hc = ho; ho = tswp;
  }

  // ---- output: h_final (fp32 = hi + lo) ----
  for (int i = bid * NTHR + tid; i < BATCH * HD; i += NBLK * NTHR)
    out[i] = unpackf(ald(hc + i));
}

extern "C" void kernel_launch(void* const* d_in, const int* in_sizes, int n_in,
                              void* d_out, int out_size, void* d_ws, size_t ws_size,
                              hipStream_t stream)
{
  const float* x   = (const float*)d_in[0];
  const float* Wih = (const float*)d_in[1];
  const float* Whh = (const float*)d_in[2];
  const float* bih = (const float*)d_in[3];
  const float* bhh = (const float*)d_in[4];
  const float* Q   = (const float*)d_in[5];
  const float* Rw  = (const float*)d_in[6];
  const float* h0  = (const float*)d_in[7];
  const float* c0  = (const float*)d_in[8];
  float* out = (float*)d_out;
  uint8_t* ws = (uint8_t*)d_ws;
  void* args[] = { &x, &Wih, &Whh, &bih, &bhh, &Q, &Rw, &h0, &c0, &out, &ws };
  hipLaunchCooperativeKernel((void*)moglstm_kernel, dim3(NBLK), dim3(NTHR),
                             args, 0, stream);
}

// Round 3
// 32243.228 us; speedup vs baseline: 2.5937x; 1.6537x over previous
//
#include <hip/hip_runtime.h>
#include <stdint.h>

#define NBLK 256
#define NTHR 512          // 8 waves: K-split within block
#define BATCH 64
#define HD 1024
#define SEQ 512

typedef unsigned short u16;
typedef uint32_t u32;
typedef __attribute__((ext_vector_type(8))) short v8s;        // 8 bf16 (MFMA A/B frag)
typedef __attribute__((ext_vector_type(4))) float v4f;        // MFMA C/D frag
typedef __attribute__((ext_vector_type(4))) unsigned int v4u; // dwordx4

__device__ __forceinline__ float bf2f(u16 u){
  union { float f; u32 i; } c; c.i = ((u32)u) << 16; return c.f;
}
__device__ __forceinline__ u16 f2bf(float f){  // round-to-nearest-even
  union { float f; u32 i; } c; c.f = f;
  u32 i = c.i;
  return (u16)((i + 0x7fffu + ((i >> 16) & 1u)) >> 16);
}
__device__ __forceinline__ float sigm(float v){ return 1.f / (1.f + __expf(-v)); }

// packed activation element: low16 = hi bf16, high16 = lo bf16; value = hi + lo
__device__ __forceinline__ u32 packf(float v){
  const u16 hi = f2bf(v);
  const u16 lo = f2bf(v - bf2f(hi));
  return (u32)hi | ((u32)lo << 16);
}
__device__ __forceinline__ float unpackf(u32 w){
  return bf2f((u16)(w & 0xffffu)) + bf2f((u16)(w >> 16));
}

// coherent (cache-bypassing) scalar access
__device__ __forceinline__ u32 ald(const u32* p){
  return __hip_atomic_load(p, __ATOMIC_RELAXED, __HIP_MEMORY_SCOPE_AGENT);
}
__device__ __forceinline__ void ast(u32* p, u32 v){
  __hip_atomic_store(p, v, __ATOMIC_RELAXED, __HIP_MEMORY_SCOPE_AGENT);
}
__device__ __forceinline__ int aldi(const int* p){
  return __hip_atomic_load(p, __ATOMIC_RELAXED, __HIP_MEMORY_SCOPE_AGENT);
}

// ---- batched coherent vector loads: N dwordx4, one waitcnt ----
// offsets: ks*128 + {0,16} bytes (lane's 8 consecutive u32 per 32-element k-step)
__device__ __forceinline__ void ald_batch8(const u32* p, v4u r[8]){
  asm volatile(
    "global_load_dwordx4 %0, %8, off sc0 sc1\n\t"
    "global_load_dwordx4 %1, %8, off offset:16 sc0 sc1\n\t"
    "global_load_dwordx4 %2, %8, off offset:128 sc0 sc1\n\t"
    "global_load_dwordx4 %3, %8, off offset:144 sc0 sc1\n\t"
    "global_load_dwordx4 %4, %8, off offset:256 sc0 sc1\n\t"
    "global_load_dwordx4 %5, %8, off offset:272 sc0 sc1\n\t"
    "global_load_dwordx4 %6, %8, off offset:384 sc0 sc1\n\t"
    "global_load_dwordx4 %7, %8, off offset:400 sc0 sc1\n\t"
    "s_waitcnt vmcnt(0)"
    : "=&v"(r[0]), "=&v"(r[1]), "=&v"(r[2]), "=&v"(r[3]),
      "=&v"(r[4]), "=&v"(r[5]), "=&v"(r[6]), "=&v"(r[7])
    : "v"(p) : "memory");
}
__device__ __forceinline__ void ald_batch16(const u32* p, v4u r[16]){
  asm volatile(
    "global_load_dwordx4 %0, %16, off sc0 sc1\n\t"
    "global_load_dwordx4 %1, %16, off offset:16 sc0 sc1\n\t"
    "global_load_dwordx4 %2, %16, off offset:128 sc0 sc1\n\t"
    "global_load_dwordx4 %3, %16, off offset:144 sc0 sc1\n\t"
    "global_load_dwordx4 %4, %16, off offset:256 sc0 sc1\n\t"
    "global_load_dwordx4 %5, %16, off offset:272 sc0 sc1\n\t"
    "global_load_dwordx4 %6, %16, off offset:384 sc0 sc1\n\t"
    "global_load_dwordx4 %7, %16, off offset:400 sc0 sc1\n\t"
    "global_load_dwordx4 %8, %16, off offset:512 sc0 sc1\n\t"
    "global_load_dwordx4 %9, %16, off offset:528 sc0 sc1\n\t"
    "global_load_dwordx4 %10, %16, off offset:640 sc0 sc1\n\t"
    "global_load_dwordx4 %11, %16, off offset:656 sc0 sc1\n\t"
    "global_load_dwordx4 %12, %16, off offset:768 sc0 sc1\n\t"
    "global_load_dwordx4 %13, %16, off offset:784 sc0 sc1\n\t"
    "global_load_dwordx4 %14, %16, off offset:896 sc0 sc1\n\t"
    "global_load_dwordx4 %15, %16, off offset:912 sc0 sc1\n\t"
    "s_waitcnt vmcnt(0)"
    : "=&v"(r[0]), "=&v"(r[1]), "=&v"(r[2]), "=&v"(r[3]),
      "=&v"(r[4]), "=&v"(r[5]), "=&v"(r[6]), "=&v"(r[7]),
      "=&v"(r[8]), "=&v"(r[9]), "=&v"(r[10]), "=&v"(r[11]),
      "=&v"(r[12]), "=&v"(r[13]), "=&v"(r[14]), "=&v"(r[15])
    : "v"(p) : "memory");
}

struct FragPair { v8s hi; v8s lo; };
// two dwordx4 of packed u32 -> (8 hi bf16, 8 lo bf16)
__device__ __forceinline__ FragPair splitpair(v4u w0, v4u w1){
  union { v8s v; u32 u[4]; } H, L;
#pragma unroll
  for (int i = 0; i < 2; i++){
    H.u[i]     = (w0[2*i] & 0xffffu) | (w0[2*i+1] << 16);
    L.u[i]     = (w0[2*i] >> 16)     | (w0[2*i+1] & 0xffff0000u);
    H.u[2 + i] = (w1[2*i] & 0xffffu) | (w1[2*i+1] << 16);
    L.u[2 + i] = (w1[2*i] >> 16)     | (w1[2*i+1] & 0xffff0000u);
  }
  FragPair f; f.hi = H.v; f.lo = L.v; return f;
}

// ---- full-grid barrier (prep only) ----
__device__ __forceinline__ void gbar_all(int* flags, int target, int bid, int tid){
  __syncthreads();
  if (tid == 0)
    __hip_atomic_store(&flags[bid], target, __ATOMIC_RELAXED, __HIP_MEMORY_SCOPE_AGENT);
  if (tid < 64){
    const int* p = flags + tid * 4;
    for (;;){
      int a = aldi(p + 0), b = aldi(p + 1), c = aldi(p + 2), d = aldi(p + 3);
      if (a >= target && b >= target && c >= target && d >= target) break;
      __builtin_amdgcn_s_sleep(1);
    }
  }
  __syncthreads();
}

// ---- 64-block row-group barrier: lane i polls member i's flag ----
__device__ __forceinline__ void gbar64(int* gf, int target, int member, int tid){
  __syncthreads();
  if (tid == 0)
    __hip_atomic_store(&gf[member], target, __ATOMIC_RELAXED, __HIP_MEMORY_SCOPE_AGENT);
  if (tid < 64){
    while (aldi(&gf[tid]) < target) __builtin_amdgcn_s_sleep(1);
  }
  __syncthreads();
}

// ---- pre-barrier weight prefetch (independent of cross-block data) ----
struct MogPre { v8s bh0, bl0, bh1, bl1; };
__device__ __forceinline__ MogPre mog_pre(const u16* WThi, const u16* WTlo, int cn, int tid){
  const int w = tid >> 6, lane = tid & 63;
  const int mi = lane & 15, q = lane >> 4;
  const int kb = w * 128 + q * 8;
  const u16* bh_p = WThi + (size_t)(cn + mi) * HD + kb;
  const u16* bl_p = WTlo + (size_t)(cn + mi) * HD + kb;
  MogPre pre;
  pre.bh0 = *(const v8s*)(bh_p);       pre.bl0 = *(const v8s*)(bl_p);
  pre.bh1 = *(const v8s*)(bh_p + 32);  pre.bl1 = *(const v8s*)(bl_p + 32);
  return pre;
}
struct GatesPre { v8s bh[4]; v8s bl[4]; };
__device__ __forceinline__ GatesPre gates_pre(
    const u16* WihThi, const u16* WihTlo,
    const u16* WhhThi, const u16* WhhTlo, int cn, int tid){
  const int w = tid >> 6, lane = tid & 63;
  const int mi = lane & 15, q = lane >> 4;
  const int src = w >> 2;
  const u16* Bh = src ? WhhThi : WihThi;
  const u16* Bl = src ? WhhTlo : WihTlo;
  const int kb = (w & 3) * 256 + q * 8;
  GatesPre g;
#pragma unroll
  for (int nt = 0; nt < 4; nt++){
    const size_t brow = (size_t)(nt * HD + cn + mi) * HD + kb;
    g.bh[nt] = *(const v8s*)(Bh + brow);
    g.bl[nt] = *(const v8s*)(Bl + brow);
  }
  return g;
}

// ---- one mogrify matmul phase: O = 2*sigmoid(A @ W) * mult ----
__device__ __forceinline__ void mog_phase(
    MogPre pre, const u32* A,
    const u16* WThi, const u16* WTlo,
    const float* multx, const u32* M, u32* O,
    int rm, int cn, int tid, float* cb)
{
  const int w = tid >> 6, lane = tid & 63;
  const int mi = lane & 15, q = lane >> 4;
  const int kb = w * 128 + q * 8;
  // epilogue multiplier: issue ASAP (produced >=2 phases ago — always ready)
  const int er = tid >> 4, ec = tid & 15;
  const int gi = (rm + er) * HD + (cn + ec);
  const bool epi = (tid < 256);
  float multv = 0.f; u32 mpack = 0;
  if (epi){
    if (multx) multv = __builtin_nontemporal_load(multx + (size_t)(rm + er) * (SEQ * HD) + (cn + ec));
    else       mpack = ald(M + gi);
  }
  // remaining B frags (plain cached loads; ks=0,1 already in pre)
  const u16* bh_p = WThi + (size_t)(cn + mi) * HD + kb;
  const u16* bl_p = WTlo + (size_t)(cn + mi) * HD + kb;
  v8s bh2 = *(const v8s*)(bh_p + 64), bl2 = *(const v8s*)(bl_p + 64);
  v8s bh3 = *(const v8s*)(bh_p + 96), bl3 = *(const v8s*)(bl_p + 96);
  // A: one batched coherent load (single MALL round trip)
  v4u ar[8];
  ald_batch8(A + (size_t)(rm + mi) * HD + kb, ar);

  v4f acc = {0.f, 0.f, 0.f, 0.f};
  FragPair a0 = splitpair(ar[0], ar[1]);
  acc = __builtin_amdgcn_mfma_f32_16x16x32_bf16(a0.hi, pre.bh0, acc, 0, 0, 0);
  acc = __builtin_amdgcn_mfma_f32_16x16x32_bf16(a0.hi, pre.bl0, acc, 0, 0, 0);
  acc = __builtin_amdgcn_mfma_f32_16x16x32_bf16(a0.lo, pre.bh0, acc, 0, 0, 0);
  FragPair a1 = splitpair(ar[2], ar[3]);
  acc = __builtin_amdgcn_mfma_f32_16x16x32_bf16(a1.hi, pre.bh1, acc, 0, 0, 0);
  acc = __builtin_amdgcn_mfma_f32_16x16x32_bf16(a1.hi, pre.bl1, acc, 0, 0, 0);
  acc = __builtin_amdgcn_mfma_f32_16x16x32_bf16(a1.lo, pre.bh1, acc, 0, 0, 0);
  FragPair a2 = splitpair(ar[4], ar[5]);
  acc = __builtin_amdgcn_mfma_f32_16x16x32_bf16(a2.hi, bh2, acc, 0, 0, 0);
  acc = __builtin_amdgcn_mfma_f32_16x16x32_bf16(a2.hi, bl2, acc, 0, 0, 0);
  acc = __builtin_amdgcn_mfma_f32_16x16x32_bf16(a2.lo, bh2, acc, 0, 0, 0);
  FragPair a3 = splitpair(ar[6], ar[7]);
  acc = __builtin_amdgcn_mfma_f32_16x16x32_bf16(a3.hi, bh3, acc, 0, 0, 0);
  acc = __builtin_amdgcn_mfma_f32_16x16x32_bf16(a3.hi, bl3, acc, 0, 0, 0);
  acc = __builtin_amdgcn_mfma_f32_16x16x32_bf16(a3.lo, bh3, acc, 0, 0, 0);

  float* dst = cb + w * 1088;            // [w][16][17] partials
#pragma unroll
  for (int r = 0; r < 4; r++) dst[(q * 4 + r) * 17 + mi] = acc[r];
  __syncthreads();
  if (epi){
    float v = 0.f;
#pragma unroll
    for (int w2 = 0; w2 < 8; w2++) v += cb[w2 * 1088 + er * 17 + ec];
    const float mult = multx ? multv : unpackf(mpack);
    ast(O + gi, packf(2.f * sigm(v) * mult));
  }
}

// ---- gates + fused LSTM cell ----
__device__ __forceinline__ void gates_phase(
    GatesPre gp, const u32* X, const u32* H,
    const u16* WihThi, const u16* WihTlo,
    const u16* WhhThi, const u16* WhhTlo,
    const float* bsum, float& creg, u32* O,
    int rm, int cn, int tid, float* cb, float* red)
{
  const int w = tid >> 6, lane = tid & 63;
  const int mi = lane & 15, q = lane >> 4;
  const int src = w >> 2;
  const u32* Ap = src ? H : X;
  const u16* Bh = src ? WhhThi : WihThi;
  const u16* Bl = src ? WhhTlo : WihTlo;
  const int kb = (w & 3) * 256 + q * 8;
  // A: batched coherent load, single waitcnt
  v4u ar[16];
  ald_batch16(Ap + (size_t)(rm + mi) * HD + kb, ar);

  const u16* bh_p[4]; const u16* bl_p[4];
#pragma unroll
  for (int nt = 0; nt < 4; nt++){
    const size_t brow = (size_t)(nt * HD + cn + mi) * HD + kb;
    bh_p[nt] = Bh + brow; bl_p[nt] = Bl + brow;
  }
  v4f acc[4];
#pragma unroll
  for (int nt = 0; nt < 4; nt++) acc[nt] = (v4f){0.f, 0.f, 0.f, 0.f};
  // ks = 0 from prefetched B
  {
    FragPair a = splitpair(ar[0], ar[1]);
#pragma unroll
    for (int nt = 0; nt < 4; nt++){
      acc[nt] = __builtin_amdgcn_mfma_f32_16x16x32_bf16(a.hi, gp.bh[nt], acc[nt], 0, 0, 0);
      acc[nt] = __builtin_amdgcn_mfma_f32_16x16x32_bf16(a.hi, gp.bl[nt], acc[nt], 0, 0, 0);
      acc[nt] = __builtin_amdgcn_mfma_f32_16x16x32_bf16(a.lo, gp.bh[nt], acc[nt], 0, 0, 0);
    }
  }
#pragma unroll
  for (int ks = 1; ks < 8; ks++){
    const int k = ks * 32;
    FragPair a = splitpair(ar[2 * ks], ar[2 * ks + 1]);
#pragma unroll
    for (int nt = 0; nt < 4; nt++){
      v8s bh = *(const v8s*)(bh_p[nt] + k);
      v8s bl = *(const v8s*)(bl_p[nt] + k);
      acc[nt] = __builtin_amdgcn_mfma_f32_16x16x32_bf16(a.hi, bh, acc[nt], 0, 0, 0);
      acc[nt] = __builtin_amdgcn_mfma_f32_16x16x32_bf16(a.hi, bl, acc[nt], 0, 0, 0);
      acc[nt] = __builtin_amdgcn_mfma_f32_16x16x32_bf16(a.lo, bh, acc[nt], 0, 0, 0);
    }
  }
#pragma unroll
  for (int nt = 0; nt < 4; nt++)
#pragma unroll
    for (int r = 0; r < 4; r++)
      cb[(w * 4 + nt) * 272 + (q * 4 + r) * 17 + mi] = acc[nt][r];
  __syncthreads();
  for (int e = tid; e < 1024; e += NTHR){
    const int qq = e >> 8, rc = e & 255, r = rc >> 4, c = rc & 15;
    float v = 0.f;
#pragma unroll
    for (int w2 = 0; w2 < 8; w2++) v += cb[(w2 * 4 + qq) * 272 + r * 17 + c];
    red[qq * 272 + r * 17 + c] = v;
  }
  __syncthreads();
  if (tid < 256){
    const int r = tid >> 4, c = tid & 15;
    const float g0 = red[0 * 272 + r * 17 + c] + bsum[0];
    const float g1 = red[1 * 272 + r * 17 + c] + bsum[1];
    const float g2 = red[2 * 272 + r * 17 + c] + bsum[2];
    const float g3 = red[3 * 272 + r * 17 + c] + bsum[3];
    const float ig = sigm(g0), fg = sigm(g1), cg = tanhf(g2), og = sigm(g3);
    const float cnew = fg * creg + ig * cg;
    creg = cnew;
    const float h = og * tanhf(cnew);
    ast(O + (rm + r) * HD + (cn + c), packf(h));
  }
}

extern "C" __global__ void __launch_bounds__(NTHR, 2)
moglstm_kernel(const float* __restrict__ x, const float* __restrict__ Wih,
               const float* __restrict__ Whh, const float* __restrict__ bih,
               const float* __restrict__ bhh, const float* __restrict__ Q,
               const float* __restrict__ Rw, const float* __restrict__ h0,
               const float* __restrict__ c0, float* __restrict__ out,
               uint8_t* __restrict__ ws)
{
  __shared__ float cb[32 * 272];
  __shared__ float red[4 * 272];
  __shared__ u16 shh[32 * 33], shl[32 * 33];

  // ---- carve workspace ----
  uint8_t* p = ws;
  u32* xA   = (u32*)p;     p += (size_t)BATCH * HD * 4;
  u32* xB   = (u32*)p;     p += (size_t)BATCH * HD * 4;
  u32* hA   = (u32*)p;     p += (size_t)BATCH * HD * 4;
  u32* hB   = (u32*)p;     p += (size_t)BATCH * HD * 4;
  u16* QThi  = (u16*)p;    p += (size_t)HD * HD * 2;
  u16* QTlo  = (u16*)p;    p += (size_t)HD * HD * 2;
  u16* RThi  = (u16*)p;    p += (size_t)HD * HD * 2;
  u16* RTlo  = (u16*)p;    p += (size_t)HD * HD * 2;
  u16* WihThi = (u16*)p;   p += (size_t)4 * HD * HD * 2;
  u16* WihTlo = (u16*)p;   p += (size_t)4 * HD * HD * 2;
  u16* WhhThi = (u16*)p;   p += (size_t)4 * HD * HD * 2;
  u16* WhhTlo = (u16*)p;   p += (size_t)4 * HD * HD * 2;
  int* flagsP = (int*)p;                 // [256] prep barrier
  int* gfbase = flagsP + 256;            // 4 groups x 256-int spaced flag arrays

  const int bid = blockIdx.x, tid = threadIdx.x;
  const int group = bid >> 6, member = bid & 63;
  const int rm = group * 16, cn = member * 16;
  int* gf = gfbase + group * 256;

  // ---- prep: split weights into hi/lo bf16 + transpose to WT[n][k]; init h ----
  for (int tile = bid; tile < 10240; tile += NBLK){
    const float* W; u16 *Th, *Tl; int N, kt, nt;
    if (tile < 1024)      { W = Q;   Th = QThi;   Tl = QTlo;   N = HD;     int tl = tile;        kt = tl >> 5; nt = tl & 31; }
    else if (tile < 2048) { W = Rw;  Th = RThi;   Tl = RTlo;   N = HD;     int tl = tile - 1024; kt = tl >> 5; nt = tl & 31; }
    else if (tile < 6144) { W = Wih; Th = WihThi; Tl = WihTlo; N = 4 * HD; int tl = tile - 2048; kt = tl >> 7; nt = tl & 127; }
    else                  { W = Whh; Th = WhhThi; Tl = WhhTlo; N = 4 * HD; int tl = tile - 6144; kt = tl >> 7; nt = tl & 127; }
    for (int e = tid; e < 1024; e += NTHR){
      const int ki = e >> 5, nj = e & 31;
      const float v = W[(size_t)(kt * 32 + ki) * N + nt * 32 + nj];
      const u16 hi = f2bf(v);
      shh[ki * 33 + nj] = hi;
      shl[ki * 33 + nj] = f2bf(v - bf2f(hi));
    }
    __syncthreads();
    for (int e = tid; e < 1024; e += NTHR){
      const int ni = e >> 5, kj = e & 31;
      Th[(size_t)(nt * 32 + ni) * HD + kt * 32 + kj] = shh[kj * 33 + ni];
      Tl[(size_t)(nt * 32 + ni) * HD + kt * 32 + kj] = shl[kj * 33 + ni];
    }
    __syncthreads();
  }
  for (int i = bid * NTHR + tid; i < BATCH * HD; i += NBLK * NTHR)
    hA[i] = packf(h0[i]);

  // hoist cell state + bias sums into registers (block<->tile mapping fixed)
  float creg = 0.f;
  float bsum[4] = {0.f, 0.f, 0.f, 0.f};
  if (tid < 256){
    const int r = tid >> 4, c = tid & 15, col = cn + c;
    creg = c0[(rm + r) * HD + col];
#pragma unroll
    for (int qq = 0; qq < 4; qq++) bsum[qq] = bih[qq * HD + col] + bhh[qq * HD + col];
  }

  // one-time heavyweight release for prep's plain stores, then full-grid barrier
  __threadfence();
  gbar_all(flagsP, 1, bid, tid);

  // ---- recurrence: 4 independent row groups, 64-block barriers ----
  u32 *hc = hA, *ho = hB;
  int bar = 0;
  MogPre pre = mog_pre(QThi, QTlo, cn, tid);
  for (int t = 0; t < SEQ; t++){
    // i=1: xt1 = 2s(ht0@Q)*x[:,t,:]
    mog_phase(pre, hc, QThi, QTlo, x + (size_t)t * HD, nullptr, xA, rm, cn, tid, cb);
    pre = mog_pre(RThi, RTlo, cn, tid);
    bar++; gbar64(gf, bar, member, tid);
    // i=2: ht1 = 2s(xt1@R)*ht0
    mog_phase(pre, xA, RThi, RTlo, nullptr, hc, ho, rm, cn, tid, cb);
    pre = mog_pre(QThi, QTlo, cn, tid);
    bar++; gbar64(gf, bar, member, tid);
    // i=3: xt2 = 2s(ht1@Q)*xt1
    mog_phase(pre, ho, QThi, QTlo, nullptr, xA, xB, rm, cn, tid, cb);
    pre = mog_pre(RThi, RTlo, cn, tid);
    bar++; gbar64(gf, bar, member, tid);
    // i=4: ht2 = 2s(xt2@R)*ht1
    mog_phase(pre, xB, RThi, RTlo, nullptr, ho, hc, rm, cn, tid, cb);
    pre = mog_pre(QThi, QTlo, cn, tid);
    bar++; gbar64(gf, bar, member, tid);
    // i=5: xt3 = 2s(ht2@Q)*xt2
    mog_phase(pre, hc, QThi, QTlo, nullptr, xB, xA, rm, cn, tid, cb);
    GatesPre gp = gates_pre(WihThi, WihTlo, WhhThi, WhhTlo, cn, tid);
    bar++; gbar64(gf, bar, member, tid);
    // gates + cell: h_new -> other h buffer
    gates_phase(gp, xA, hc, WihThi, WihTlo, WhhThi, WhhTlo, bsum, creg, ho,
                rm, cn, tid, cb, red);
    pre = mog_pre(QThi, QTlo, cn, tid);
    bar++; gbar64(gf, bar, member, tid);
    u32* tswp = hc; hc = ho; ho = tswp;
  }

  // ---- output: each block writes its own 16x16 tile of h_final ----
  if (tid < 256){
    const int er = tid >> 4, ec = tid & 15;
    const int gi = (rm + er) * HD + (cn + ec);
    out[gi] = unpackf(ald(hc + gi));
  }
}

extern "C" void kernel_launch(void* const* d_in, const int* in_sizes, int n_in,
                              void* d_out, int out_size, void* d_ws, size_t ws_size,
                              hipStream_t stream)
{
  const float* x   = (const float*)d_in[0];
  const float* Wih = (const float*)d_in[1];
  const float* Whh = (const float*)d_in[2];
  const float* bih = (const float*)d_in[3];
  const float* bhh = (const float*)d_in[4];
  const float* Q   = (const float*)d_in[5];
  const float* Rw  = (const float*)d_in[6];
  const float* h0  = (const float*)d_in[7];
  const float* c0  = (const float*)d_in[8];
  float* out = (float*)d_out;
  uint8_t* ws = (uint8_t*)d_ws;
  void* args[] = { &x, &Wih, &Whh, &bih, &bhh, &Q, &Rw, &h0, &c0, &out, &ws };
  hipLaunchCooperativeKernel((void*)moglstm_kernel, dim3(NBLK), dim3(NTHR),
                             args, 0, stream);
}